// Round 16
// baseline (102.858 us; speedup 1.0000x reference)
//
#include <hip/hip_runtime.h>
#include <cmath>

// ============================================================================
// DIAGNOSTIC ROUND (r16): every kernel of the r14 best-known pipeline (33.53us)
// is repeated idempotently to lift it above the ~39us fill-dispatch rocprof
// cutoff: K1 x15, K2 x3 (ct-loop, ptr reset), K3 x20 (atomics once, last rep).
// Outputs bit-identical to r14. Next round reverts REPs and exploits counters.
// ============================================================================
#define REP1 15
#define REP2 3
#define REP3 20

#define BN 8192
#define DIM 128
#define MARGIN_F 0.3f
#define NSPLIT 8            // column splits (1024 cols each)
#define CPS 1024
#define NT 8                // 128-col B tiles per panel
#define NPART (NSPLIT * 2)  // per-row partials: split x wc
#define FBLK 32
#define IMAX 0x7FFFFFFF
#define IMIN 0x80000000

typedef __attribute__((ext_vector_type(4))) int i32x4;

__device__ __forceinline__ int imin3(int a, int b, int c) { return min(a, min(b, c)); }
__device__ __forceinline__ int imax3(int a, int b, int c) { return max(a, max(b, c)); }

// ---------------- K1 x REP1: fp32 row norms -> sqv + k-major i8 quantized copy ----------------
__global__ __launch_bounds__(256) void norm_cvt_k(
    const float* __restrict__ emb, const int* __restrict__ lab,
    float* __restrict__ sqv, unsigned short* __restrict__ EnQ16,
    unsigned* __restrict__ LP, float* __restrict__ gacc)
{
  int gt = blockIdx.x * blockDim.x + threadIdx.x;
  int w = gt >> 6;            // one wave per row (grid exact: w < BN always)
  int lane = threadIdx.x & 63;

  #pragma unroll 1
  for (int rep = 0; rep < REP1; ++rep) {
    if (gt < 3) gacc[gt] = 0.f;
    if (gt < 2048) {
      int base = (gt >> 4) * 64 + (gt & 15);
      LP[gt] = (unsigned)(lab[base] & 255) | ((unsigned)(lab[base + 16] & 255) << 8) |
               ((unsigned)(lab[base + 32] & 255) << 16) | ((unsigned)(lab[base + 48] & 255) << 24);
    }
    float2 v = *reinterpret_cast<const float2*>(&emb[w * DIM + lane * 2]);
    float s = v.x * v.x + v.y * v.y;
    #pragma unroll
    for (int off = 32; off > 0; off >>= 1) s += __shfl_xor(s, off);
    float iv = 1.0f / fmaxf(sqrtf(s), 1e-12f);
    if (lane == 0) sqv[w] = s * iv * iv;
    int q0 = (int)rintf(127.0f * v.x * iv);
    int q1 = (int)rintf(127.0f * v.y * iv);
    unsigned short us = (unsigned short)((q0 & 255) | ((q1 & 255) << 8));
    int g = lane >> 3;
    EnQ16[(g * BN + w) * 8 + (lane & 7)] = us;
    asm volatile("" ::: "memory");   // defeat cross-rep load hoisting
  }
}

// ---------------- K2 x REP2: barrier-free i8-MFMA gram + hard mining (r8/r14 structure) ----------------
__global__ __launch_bounds__(256, 2) void gram_mine_mfma_k(
    const char* __restrict__ EnQ, const int* __restrict__ lab,
    const unsigned* __restrict__ LP,
    int* __restrict__ ap_part, int* __restrict__ an_part)
{
  const int tid = threadIdx.x;
  const int w = tid >> 6, l = tid & 63;
  const int wr = w >> 1, wc = w & 1;
  const int lrow = l & 15, lkg = l >> 4;

  const int rowBase = blockIdx.x * 128 + wr * 64;
  const int panel   = blockIdx.y * CPS;

  i32x4 a[4][2];
  #pragma unroll
  for (int mi = 0; mi < 4; ++mi)
    #pragma unroll
    for (int kk = 0; kk < 2; ++kk)
      a[mi][kk] = *reinterpret_cast<const i32x4*>(
          EnQ + (((size_t)((kk << 2) + lkg) * BN + rowBase + mi * 16 + lrow) << 4));

  int rlv[4][4];
  #pragma unroll
  for (int mi = 0; mi < 4; ++mi) {
    int rb = rowBase + mi * 16 + lkg * 4;
    #pragma unroll
    for (int r = 0; r < 4; ++r) rlv[mi][r] = lab[rb + r] & 255;
  }

  int ap[4][4], an[4][4];
  #pragma unroll
  for (int mi = 0; mi < 4; ++mi)
    #pragma unroll
    for (int r = 0; r < 4; ++r) { ap[mi][r] = IMAX; an[mi][r] = IMIN; }

  const i32x4 zf = {0, 0, 0, 0};
  const int colLane = wc * 64 + lrow;
  const char* const bp0_0 = EnQ + (((size_t)lkg * BN + panel + colLane) << 4);
  const char* const bp1_0 = bp0_0 + ((size_t)BN << 6);

  auto loadHalf = [&](i32x4 (&b)[2][2], const char* p0, const char* p1, int n0) {
    #pragma unroll
    for (int n = 0; n < 2; ++n) {
      b[0][n] = *reinterpret_cast<const i32x4*>(p0 + (n0 + n) * 256);
      b[1][n] = *reinterpret_cast<const i32x4*>(p1 + (n0 + n) * 256);
    }
  };
  auto mfmaHalf = [&](i32x4 (&A)[4][2], const i32x4 (&b)[2][2]) {
    #pragma unroll
    for (int mi = 0; mi < 4; ++mi)
      #pragma unroll
      for (int n = 0; n < 2; ++n)
        A[mi][n] = __builtin_amdgcn_mfma_i32_16x16x64_i8(a[mi][0], b[0][n], zf, 0, 0, 0);
    #pragma unroll
    for (int mi = 0; mi < 4; ++mi)
      #pragma unroll
      for (int n = 0; n < 2; ++n)
        A[mi][n] = __builtin_amdgcn_mfma_i32_16x16x64_i8(a[mi][1], b[1][n], A[mi][n], 0, 0, 0);
  };
  auto mineTile = [&](const i32x4 (&A)[4][2], int l0, int l1, int c0, int c1, bool dg) {
    if (!dg) {
      #pragma unroll
      for (int mi = 0; mi < 4; ++mi)
        #pragma unroll
        for (int r = 0; r < 4; ++r) {
          int d0 = A[mi][0][r], d1 = A[mi][1][r];
          bool s0 = (rlv[mi][r] == l0), s1 = (rlv[mi][r] == l1);
          int p0 = s0 ? d0 : IMAX;
          int p1 = s1 ? d1 : IMAX;
          int q0 = s0 ? IMIN : d0;
          int q1 = s1 ? IMIN : d1;
          ap[mi][r] = imin3(ap[mi][r], p0, p1);
          an[mi][r] = imax3(an[mi][r], q0, q1);
        }
    } else {
      #pragma unroll
      for (int mi = 0; mi < 4; ++mi)
        #pragma unroll
        for (int r = 0; r < 4; ++r) {
          int rloc = mi * 16 + lkg * 4 + r;
          int d0 = A[mi][0][r], d1 = A[mi][1][r];
          bool s0 = (rlv[mi][r] == l0), s1 = (rlv[mi][r] == l1);
          bool e0 = (rloc == c0), e1 = (rloc == c1);
          int p0 = (s0 && !e0) ? d0 : IMAX;
          int p1 = (s1 && !e1) ? d1 : IMAX;
          int q0 = s0 ? IMIN : d0;
          int q1 = s1 ? IMIN : d1;
          ap[mi][r] = imin3(ap[mi][r], p0, p1);
          an[mi][r] = imax3(an[mi][r], q0, q1);
        }
    }
  };

  #pragma unroll 1
  for (int rep = 0; rep < REP2; ++rep) {
    const char* bp0 = bp0_0;
    const char* bp1 = bp1_0;
    i32x4 accA[4][2], accB[4][2];
    i32x4 bA[2][2], bB[2][2];
    int lprev0 = 0, lprev1 = 0;
    bool diagP = false;

    loadHalf(bA, bp0, bp1, 0);

    #pragma unroll 1
    for (int ct = 0; ct < NT; ++ct) {
      const int colBase = panel + ct * 128 + wc * 64;
      const bool diag = (rowBase == colBase);

      const unsigned LPv = LP[(colBase >> 6) * 16 + lrow];
      const int l0 = (int)(LPv & 255u),         l1 = (int)((LPv >> 8) & 255u);
      const int l2 = (int)((LPv >> 16) & 255u), l3 = (int)(LPv >> 24);

      loadHalf(bB, bp0, bp1, 2);
      mfmaHalf(accA, bA);
      if (ct > 0) mineTile(accB, lprev0, lprev1, 32 + lrow, 48 + lrow, diagP);

      bp0 += 2048; bp1 += 2048;
      if (ct + 1 < NT) loadHalf(bA, bp0, bp1, 0);

      mfmaHalf(accB, bB);
      mineTile(accA, l0, l1, 0 + lrow, 16 + lrow, diag);

      lprev0 = l2; lprev1 = l3; diagP = diag;
    }
    mineTile(accB, lprev0, lprev1, 32 + lrow, 48 + lrow, diagP);
    asm volatile("" ::: "memory");
  }

  const int part = blockIdx.y * 2 + wc;
  #pragma unroll
  for (int mi = 0; mi < 4; ++mi)
    #pragma unroll
    for (int r = 0; r < 4; ++r) {
      int p = ap[mi][r], n = an[mi][r];
      #pragma unroll
      for (int off = 1; off < 16; off <<= 1) {
        p = min(p, __shfl_xor(p, off));
        n = max(n, __shfl_xor(n, off));
      }
      if (lrow == 0) {
        int rg = rowBase + mi * 16 + lkg * 4 + r;
        ap_part[part * BN + rg] = p;
        an_part[part * BN + rg] = n;
      }
    }
}

// ---------------- K3 x REP3: per-row combine + fused final scalar (atomics once) ----------------
__global__ __launch_bounds__(256) void finalize_k(
    const int* __restrict__ ap_part, const int* __restrict__ an_part,
    const float* __restrict__ sqv,
    float* __restrict__ gacc, float* __restrict__ out)
{
  int r = blockIdx.x * 256 + threadIdx.x;
  float sum = 0.f, cnt = 0.f;

  #pragma unroll 1
  for (int rep = 0; rep < REP3; ++rep) {
    int apt = IMAX, ant = IMIN;
    #pragma unroll 8
    for (int s = 0; s < NPART; ++s) {
      apt = min(apt, ap_part[s * BN + r]);
      ant = max(ant, an_part[s * BN + r]);
    }
    sum = 0.f; cnt = 0.f;
    if (apt != IMAX && ant != IMIN) {
      const float sc = 2.0f / (127.0f * 127.0f);
      float rs1 = sqv[r] + 1.0f;
      float dap = sqrtf(fmaxf(fmaf(-sc, (float)apt, rs1), 0.f));
      float dan = sqrtf(fmaxf(fmaf(-sc, (float)ant, rs1), 0.f));
      sum = fmaxf(dap - dan + MARGIN_F, 0.f);
      cnt = 1.f;
    }
    asm volatile("" ::: "memory");
  }

  #pragma unroll
  for (int off = 32; off > 0; off >>= 1) {
    sum += __shfl_xor(sum, off);
    cnt += __shfl_xor(cnt, off);
  }
  __shared__ float ssum[4], scnt[4];
  int wv = threadIdx.x >> 6;
  if ((threadIdx.x & 63) == 0) { ssum[wv] = sum; scnt[wv] = cnt; }
  __syncthreads();
  if (threadIdx.x == 0) {
    float bs = ssum[0] + ssum[1] + ssum[2] + ssum[3];
    float bc = scnt[0] + scnt[1] + scnt[2] + scnt[3];
    atomicAdd(&gacc[0], bs);
    atomicAdd(&gacc[1], bc);
    __threadfence();
    int old = atomicAdd((int*)&gacc[2], 1);
    if (old == FBLK - 1) {
      __threadfence();
      float s = atomicAdd(&gacc[0], 0.f);
      float c = atomicAdd(&gacc[1], 0.f);
      out[0] = (c > 0.f) ? (s / c) : 0.f;
      gacc[0] = 0.f; gacc[1] = 0.f; *(int*)&gacc[2] = 0;
    }
  }
}

extern "C" void kernel_launch(void* const* d_in, const int* in_sizes, int n_in,
                              void* d_out, int out_size, void* d_ws, size_t ws_size,
                              hipStream_t stream)
{
  const float* emb = (const float*)d_in[0];
  const int*   lab = (const int*)d_in[1];
  float* out = (float*)d_out;
  float* ws  = (float*)d_ws;

  float*    sqv     = ws;                          // BN floats
  int*      ap_part = (int*)(sqv + BN);            // NPART*BN ints
  int*      an_part = ap_part + NPART * BN;        // NPART*BN ints
  unsigned* LP      = (unsigned*)(an_part + NPART * BN);  // 2048 u32 (8 KB)
  float*    gacc    = (float*)(LP + 2048);         // gsum, gcnt, gctr
  char*     EnQ     = (char*)(gacc + 16);          // BN*DIM i8, k-major (~1 MB)

  norm_cvt_k<<<dim3(BN / 4), 256, 0, stream>>>(emb, lab, sqv, (unsigned short*)EnQ, LP, gacc);
  gram_mine_mfma_k<<<dim3(BN / 128, NSPLIT), 256, 0, stream>>>(EnQ, lab, LP, ap_part, an_part);
  finalize_k<<<dim3(FBLK), 256, 0, stream>>>(ap_part, an_part, sqv, gacc, out);
}